// Round 8
// baseline (466.048 us; speedup 1.0000x reference)
//
#include <hip/hip_runtime.h>
#include <stdint.h>

#define M_DIM 8192
#define K_DIM 4096
#define N_DIM 4096
#define KTILES (K_DIM / 64)

typedef __attribute__((ext_vector_type(4))) int i32x4;

// ---------------------------------------------------------------------------
// Pack int32-stored int8 weights [N,K] -> true int8 [N,K]; per-row sum folded
// into integer correction corr[n] = (128 - zp) * rowsum[n].
// ---------------------------------------------------------------------------
__global__ void pack_w_kernel(const int* __restrict__ w, char* __restrict__ wp,
                              int* __restrict__ corr, const int* __restrict__ zpp) {
  __shared__ int red[256];
  const int n = blockIdx.x;
  const int t = threadIdx.x;
  const int4* row = (const int4*)(w + (size_t)n * K_DIM);
  int s = 0;
  int words[4];
#pragma unroll
  for (int u = 0; u < 4; ++u) {
    int4 v = row[t * 4 + u];
    s += v.x + v.y + v.z + v.w;
    words[u] = (v.x & 255) | ((v.y & 255) << 8) | ((v.z & 255) << 16) | (v.w << 24);
  }
  ((int4*)(wp + (size_t)n * K_DIM))[t] = make_int4(words[0], words[1], words[2], words[3]);
  red[t] = s;
  __syncthreads();
  for (int off = 128; off > 0; off >>= 1) {
    if (t < off) red[t] += red[t + off];
    __syncthreads();
  }
  if (t == 0) corr[n] = (128 - zpp[0]) * red[0];
}

// ---------------------------------------------------------------------------
// Quantize fp32 input -> int8 (q - 128), 4 elements/thread.
// ---------------------------------------------------------------------------
__global__ void quant_in_kernel(const float* __restrict__ x, char* __restrict__ q,
                                const float* __restrict__ sp, const int* __restrict__ zpp) {
  const int i = blockIdx.x * blockDim.x + threadIdx.x;
  const float s = sp[0];
  const float zp = (float)zpp[0];
  float4 v = ((const float4*)x)[i];
  float t0 = fminf(fmaxf(rintf(v.x / s) + zp, 0.f), 255.f);
  float t1 = fminf(fmaxf(rintf(v.y / s) + zp, 0.f), 255.f);
  float t2 = fminf(fmaxf(rintf(v.z / s) + zp, 0.f), 255.f);
  float t3 = fminf(fmaxf(rintf(v.w / s) + zp, 0.f), 255.f);
  int b0 = (int)t0 - 128, b1 = (int)t1 - 128, b2 = (int)t2 - 128, b3 = (int)t3 - 128;
  ((int*)q)[i] = (b0 & 255) | ((b1 & 255) << 8) | ((b2 & 255) << 16) | (b3 << 24);
}

// ---------------------------------------------------------------------------
// 256x256 i8 GEMM = R3 core + (1) wave-group stagger, (2) full-line epilogue.
// R8 = R7 with TILEB's dropped STAGE16(asrc1,...) restored (R7 fail cause:
// group-B waves staged only 3/4 chunks -> A rows 192-255 stale, absmax 1888).
// (1) waves 0-3 (group A): [reads][MFMA c0][reads][MFMA c1] (R3 order);
//     waves 4-7 (group B): [MFMA c0][reads][MFMA c1][reads]. SIMD k hosts
//     waves k,k+4 -> one wave on matrix pipe while sibling drives LDS.
// (2) B content permutation: LDS row (b+16j+r) holds weight row (b+4r+j)
//     (only the per-lane staging SOURCE address changes; ds_read pattern and
//     0-conflict swizzle unchanged). Output frag j, lane c -> n = base+4c+j:
//     int8 packs one u32, fp32 one float4 -> full-line stores (kills RMW).
// Ring/ledger (R3-proven): 4-slot ring, prefetch distance 3; slots t,t+1
// confirmed at tile-t start; vmcnt(4) per tile (4 stages/tile both groups)
// confirms t+2; barrier separates a slot's last reads from its overwrite.
// ---------------------------------------------------------------------------
#define STAGE16(SRC, DST)                                                     \
  __builtin_amdgcn_global_load_lds(                                           \
      (const __attribute__((address_space(1))) void*)(SRC),                   \
      (__attribute__((address_space(3))) void*)(DST), 16, 0, 0)

#define RD(p) (*(const i32x4*)(p))

#define MFMA_C0                                                               \
  __builtin_amdgcn_s_setprio(1);                                              \
  _Pragma("unroll") for (int i_ = 0; i_ < 4; ++i_)                            \
      _Pragma("unroll") for (int j_ = 0; j_ < 4; ++j_)                        \
          acc[i_][j_] = __builtin_amdgcn_mfma_i32_16x16x64_i8(                \
              a0[i_], b0[j_], acc[i_][j_], 0, 0, 0);                          \
  __builtin_amdgcn_s_setprio(0);

#define MFMA_C1(A1)                                                           \
  __builtin_amdgcn_s_setprio(1);                                              \
  _Pragma("unroll") for (int i_ = 0; i_ < 4; ++i_)                            \
      _Pragma("unroll") for (int j_ = 0; j_ < 4; ++j_)                        \
          acc[4 + i_][j_] = __builtin_amdgcn_mfma_i32_16x16x64_i8(            \
              A1[i_], b0[j_], acc[4 + i_][j_], 0, 0, 0);                      \
  __builtin_amdgcn_s_setprio(0);

// Group A: [a1 reads + stageA] [c0] [next reads + stageB] [c1]  (R3 order)
#define TILEA(SLOT, KSTG, DO_NEXT)                                            \
  {                                                                           \
    const char* bufA_ = &lds[SLOT][0][0];                                     \
    char* nA_ = &lds[((SLOT) + 3) & 3][0][0];                                 \
    char* nB_ = &lds[((SLOT) + 3) & 3][1][0];                                 \
    i32x4 a1_[4];                                                             \
    _Pragma("unroll") for (int i_ = 0; i_ < 4; ++i_)                          \
        a1_[i_] = RD(bufA_ + aoff[4 + i_]);                                   \
    STAGE16(asrc0 + (size_t)(KSTG) * 64, nA_ + o0_);                          \
    STAGE16(asrc1 + (size_t)(KSTG) * 64, nA_ + o1_);                          \
    __builtin_amdgcn_sched_barrier(0);                                        \
    MFMA_C0                                                                   \
    i32x4 ta_[4], tb_[4];                                                     \
    if (DO_NEXT) {                                                            \
      const char* xA_ = &lds[((SLOT) + 1) & 3][0][0];                         \
      const char* xB_ = &lds[((SLOT) + 1) & 3][1][0];                         \
      _Pragma("unroll") for (int i_ = 0; i_ < 4; ++i_)                        \
          ta_[i_] = RD(xA_ + aoff[i_]);                                       \
      _Pragma("unroll") for (int j_ = 0; j_ < 4; ++j_)                        \
          tb_[j_] = RD(xB_ + boff[j_]);                                       \
    }                                                                         \
    STAGE16(bsrc0 + (size_t)(KSTG) * 64, nB_ + o0_);                          \
    STAGE16(bsrc1 + (size_t)(KSTG) * 64, nB_ + o1_);                          \
    __builtin_amdgcn_sched_barrier(0);                                        \
    MFMA_C1(a1_)                                                              \
    asm volatile("s_waitcnt vmcnt(4)" ::: "memory");                          \
    __builtin_amdgcn_s_barrier();                                             \
    if (DO_NEXT) {                                                            \
      _Pragma("unroll") for (int i_ = 0; i_ < 4; ++i_) a0[i_] = ta_[i_];      \
      _Pragma("unroll") for (int j_ = 0; j_ < 4; ++j_) b0[j_] = tb_[j_];      \
    }                                                                         \
  }

// Group B: [c0] [a1 reads + stageA] [c1] [next reads + stageB]  (staggered)
#define TILEB(SLOT, KSTG, DO_NEXT)                                            \
  {                                                                           \
    const char* bufA_ = &lds[SLOT][0][0];                                     \
    char* nA_ = &lds[((SLOT) + 3) & 3][0][0];                                 \
    char* nB_ = &lds[((SLOT) + 3) & 3][1][0];                                 \
    MFMA_C0                                                                   \
    __builtin_amdgcn_sched_barrier(0);                                        \
    i32x4 a1_[4];                                                             \
    _Pragma("unroll") for (int i_ = 0; i_ < 4; ++i_)                          \
        a1_[i_] = RD(bufA_ + aoff[4 + i_]);                                   \
    STAGE16(asrc0 + (size_t)(KSTG) * 64, nA_ + o0_);                          \
    STAGE16(asrc1 + (size_t)(KSTG) * 64, nA_ + o1_);                          \
    __builtin_amdgcn_sched_barrier(0);                                        \
    MFMA_C1(a1_)                                                              \
    __builtin_amdgcn_sched_barrier(0);                                        \
    if (DO_NEXT) {                                                            \
      const char* xA_ = &lds[((SLOT) + 1) & 3][0][0];                         \
      const char* xB_ = &lds[((SLOT) + 1) & 3][1][0];                         \
      _Pragma("unroll") for (int i_ = 0; i_ < 4; ++i_)                        \
          a0[i_] = RD(xA_ + aoff[i_]);                                        \
      _Pragma("unroll") for (int j_ = 0; j_ < 4; ++j_)                        \
          b0[j_] = RD(xB_ + boff[j_]);                                        \
    }                                                                         \
    STAGE16(bsrc0 + (size_t)(KSTG) * 64, nB_ + o0_);                          \
    STAGE16(bsrc1 + (size_t)(KSTG) * 64, nB_ + o1_);                          \
    asm volatile("s_waitcnt vmcnt(4)" ::: "memory");                          \
    __builtin_amdgcn_s_barrier();                                             \
  }

template <int WRITE_Q>
__global__ __launch_bounds__(512, 2) void gemm_kernel(
    const char* __restrict__ qa, const char* __restrict__ wb,
    const int* __restrict__ corr, const float* __restrict__ swp,
    const float* __restrict__ bias, const float* __restrict__ sp,
    const int* __restrict__ zpp, char* __restrict__ outq, float* __restrict__ outf) {
  __shared__ __align__(16) char lds[4][2][16384];  // 128 KB: 4-slot ring
  const int tid = threadIdx.x;
  const int lane = tid & 63;
  const int w = tid >> 6;
  const int wr = w >> 2;          // 0..1 (M)
  const int wc = w & 3;           // 0..3 (N)
  const int wgrp = (w >> 2) & 1;  // stagger group: SIMD k hosts waves k, k+4
  const int bid = blockIdx.x;
  const int bm = bid & 31;  // M/256 = 32, fastest: neighbors share B panel
  const int bn = bid >> 5;  // N/256 = 16
  const char* abase = qa + (size_t)bm * 256 * K_DIM;
  const char* bbase = wb + (size_t)bn * 256 * K_DIM;

  // --- per-thread staging constants (inverse-swizzled global sources) ---
  const int o0_ = tid * 16;
  const int o1_ = 8192 + tid * 16;
  const int r0_ = o0_ >> 6, r1_ = o1_ >> 6;
  const int g0_ = ((o0_ >> 4) & 3) ^ ((r0_ >> 1) & 3);
  const int g1_ = ((o1_ >> 4) & 3) ^ ((r1_ >> 1) & 3);
  const char* asrc0 = abase + (size_t)r0_ * K_DIM + g0_ * 16;
  const char* asrc1 = abase + (size_t)r1_ * K_DIM + g1_ * 16;
  // B content permutation: LDS row rho holds weight row (rho&~63)+4*(rho&15)+((rho>>4)&3)
  const int p0_ = (r0_ & ~63) + 4 * (r0_ & 15) + ((r0_ >> 4) & 3);
  const int p1_ = (r1_ & ~63) + 4 * (r1_ & 15) + ((r1_ >> 4) & 3);
  const char* bsrc0 = bbase + (size_t)p0_ * K_DIM + g0_ * 16;
  const char* bsrc1 = bbase + (size_t)p1_ * K_DIM + g1_ * 16;

  // --- per-thread ds_read byte offsets (swizzled; pattern unchanged) ---
  const int rr = lane & 15;
  const int g = lane >> 4;
  int aoff[8], boff[4];
#pragma unroll
  for (int i = 0; i < 8; ++i) {
    const int row = wr * 128 + i * 16 + rr;
    aoff[i] = (row << 6) + ((g ^ ((row >> 1) & 3)) << 4);
  }
#pragma unroll
  for (int j = 0; j < 4; ++j) {
    const int row = wc * 64 + j * 16 + rr;
    boff[j] = (row << 6) + ((g ^ ((row >> 1) & 3)) << 4);
  }

  i32x4 acc[8][4] = {};

  // --- prologue: stage slots 0,1,2 (tiles 0,1,2); confirm slots 0 AND 1 ---
  STAGE16(asrc0, &lds[0][0][o0_]); STAGE16(asrc1, &lds[0][0][o1_]);
  STAGE16(bsrc0, &lds[0][1][o0_]); STAGE16(bsrc1, &lds[0][1][o1_]);
  STAGE16(asrc0 + 64, &lds[1][0][o0_]); STAGE16(asrc1 + 64, &lds[1][0][o1_]);
  STAGE16(bsrc0 + 64, &lds[1][1][o0_]); STAGE16(bsrc1 + 64, &lds[1][1][o1_]);
  STAGE16(asrc0 + 128, &lds[2][0][o0_]); STAGE16(asrc1 + 128, &lds[2][0][o1_]);
  STAGE16(bsrc0 + 128, &lds[2][1][o0_]); STAGE16(bsrc1 + 128, &lds[2][1][o1_]);
  asm volatile("s_waitcnt vmcnt(4)" ::: "memory");  // slots 0,1 confirmed
  __builtin_amdgcn_s_barrier();

  i32x4 a0[4], b0[4];
#pragma unroll
  for (int i = 0; i < 4; ++i) a0[i] = RD(&lds[0][0][0] + aoff[i]);
#pragma unroll
  for (int j = 0; j < 4; ++j) b0[j] = RD(&lds[0][1][0] + boff[j]);

  // --- main loop (wave-group staggered orders; barrier counts identical) ---
  if (wgrp == 0) {
    for (int tb = 0; tb < (KTILES - 4) / 4; ++tb) {
      const int t0 = tb * 4;
#pragma unroll
      for (int u = 0; u < 4; ++u) { TILEA(u, t0 + u + 3, 1); }
    }
    TILEA(0, KTILES - 1, 1);
    TILEA(1, KTILES - 1, 1);
    TILEA(2, KTILES - 1, 1);
    TILEA(3, KTILES - 1, 0);
  } else {
    for (int tb = 0; tb < (KTILES - 4) / 4; ++tb) {
      const int t0 = tb * 4;
#pragma unroll
      for (int u = 0; u < 4; ++u) { TILEB(u, t0 + u + 3, 1); }
    }
    TILEB(0, KTILES - 1, 1);
    TILEB(1, KTILES - 1, 1);
    TILEB(2, KTILES - 1, 1);
    TILEB(3, KTILES - 1, 0);
  }
  asm volatile("s_waitcnt vmcnt(0)" ::: "memory");  // drain before exit

  // --- epilogue: frag j, lane c -> n = nb4 + j (consecutive) ---
  // C/D layout: col-within-frag = lane&15 = c, row m = (lane>>4)*4 + reg.
  const float s = sp[0];
  const float zpf = (float)zpp[0];
  const int m0 = bm * 256 + wr * 128 + (lane >> 4) * 4;
  const int nb4 = bn * 256 + wc * 64 + ((lane & 15) << 2);
  const int4 cr4 = *(const int4*)(corr + nb4);
  const float4 sw4 = *(const float4*)(swp + nb4);
  const float4 bb4 = *(const float4*)(bias + nb4);
  const float fs0 = s * sw4.x, fs1 = s * sw4.y, fs2 = s * sw4.z, fs3 = s * sw4.w;
#pragma unroll
  for (int i = 0; i < 8; ++i) {
#pragma unroll
    for (int q = 0; q < 4; ++q) {
      const int m = m0 + i * 16 + q;
      const float v0 = fs0 * (float)(acc[i][0][q] + cr4.x) + bb4.x;
      const float v1 = fs1 * (float)(acc[i][1][q] + cr4.y) + bb4.y;
      const float v2 = fs2 * (float)(acc[i][2][q] + cr4.z) + bb4.z;
      const float v3 = fs3 * (float)(acc[i][3][q] + cr4.w) + bb4.w;
      if (WRITE_Q) {
        const int b0i = (int)fminf(fmaxf(rintf(v0 / s) + zpf, 0.f), 255.f) - 128;
        const int b1i = (int)fminf(fmaxf(rintf(v1 / s) + zpf, 0.f), 255.f) - 128;
        const int b2i = (int)fminf(fmaxf(rintf(v2 / s) + zpf, 0.f), 255.f) - 128;
        const int b3i = (int)fminf(fmaxf(rintf(v3 / s) + zpf, 0.f), 255.f) - 128;
        const uint32_t pk = (uint32_t)(b0i & 255) | ((uint32_t)(b1i & 255) << 8) |
                            ((uint32_t)(b2i & 255) << 16) | ((uint32_t)b3i << 24);
        *(uint32_t*)(outq + (size_t)m * N_DIM + nb4) = pk;
      } else {
        float4 o4;
        o4.x = v0; o4.y = v1; o4.z = v2; o4.w = v3;
        *(float4*)(outf + (size_t)m * N_DIM + nb4) = o4;
      }
    }
  }
}

// ---------------------------------------------------------------------------
extern "C" void kernel_launch(void* const* d_in, const int* in_sizes, int n_in,
                              void* d_out, int out_size, void* d_ws, size_t ws_size,
                              hipStream_t stream) {
  const float* x = (const float*)d_in[0];
  const int* wq = (const int*)d_in[1];
  const float* bias = (const float*)d_in[2];
  const float* s_in = (const float*)d_in[3];
  const int* zp_in = (const int*)d_in[4];
  const float* s_w = (const float*)d_in[5];
  float* out = (float*)d_out;

  const size_t WP_BYTES = (size_t)N_DIM * K_DIM;  // 16 MB packed int8 W
  const size_t Q_BYTES = (size_t)M_DIM * K_DIM;   // 32 MB int8 activations
  char* ws = (char*)d_ws;
  char* wp = ws;
  char* q1 = ws + WP_BYTES;
  char* q2 = q1 + Q_BYTES;
  int* corr = (int*)(q2 + Q_BYTES);
  const size_t NEEDED = WP_BYTES + 2 * Q_BYTES + (size_t)N_DIM * sizeof(int);
  if (ws_size < NEEDED) return;

  pack_w_kernel<<<N_DIM, 256, 0, stream>>>(wq, wp, corr, zp_in);
  quant_in_kernel<<<(M_DIM * K_DIM / 4) / 256, 256, 0, stream>>>(x, q1, s_in, zp_in);

  dim3 grid((M_DIM / 256) * (N_DIM / 256));  // 512 blocks
  dim3 blk(512);
  gemm_kernel<1><<<grid, blk, 0, stream>>>(q1, wp, corr, s_w, bias, s_in, zp_in, q2, nullptr);
  gemm_kernel<1><<<grid, blk, 0, stream>>>(q2, wp, corr, s_w, bias, s_in, zp_in, q1, nullptr);
  gemm_kernel<0><<<grid, blk, 0, stream>>>(q1, wp, corr, s_w, bias, s_in, zp_in, nullptr, out);
}

// Round 9
// 441.988 us; speedup vs baseline: 1.0544x; 1.0544x over previous
//
#include <hip/hip_runtime.h>
#include <stdint.h>

#define M_DIM 8192
#define K_DIM 4096
#define N_DIM 4096
#define KTILES (K_DIM / 64)

typedef __attribute__((ext_vector_type(4))) int i32x4;

// ---------------------------------------------------------------------------
// Pack int32-stored int8 weights [N,K] -> true int8 [N,K]; per-row sum folded
// into integer correction corr[n] = (128 - zp) * rowsum[n].
// ---------------------------------------------------------------------------
__global__ void pack_w_kernel(const int* __restrict__ w, char* __restrict__ wp,
                              int* __restrict__ corr, const int* __restrict__ zpp) {
  __shared__ int red[256];
  const int n = blockIdx.x;
  const int t = threadIdx.x;
  const int4* row = (const int4*)(w + (size_t)n * K_DIM);
  int s = 0;
  int words[4];
#pragma unroll
  for (int u = 0; u < 4; ++u) {
    int4 v = row[t * 4 + u];
    s += v.x + v.y + v.z + v.w;
    words[u] = (v.x & 255) | ((v.y & 255) << 8) | ((v.z & 255) << 16) | (v.w << 24);
  }
  ((int4*)(wp + (size_t)n * K_DIM))[t] = make_int4(words[0], words[1], words[2], words[3]);
  red[t] = s;
  __syncthreads();
  for (int off = 128; off > 0; off >>= 1) {
    if (t < off) red[t] += red[t + off];
    __syncthreads();
  }
  if (t == 0) corr[n] = (128 - zpp[0]) * red[0];
}

// ---------------------------------------------------------------------------
// Quantize fp32 input -> int8 (q - 128), 4 elements/thread.
// ---------------------------------------------------------------------------
__global__ void quant_in_kernel(const float* __restrict__ x, char* __restrict__ q,
                                const float* __restrict__ sp, const int* __restrict__ zpp) {
  const int i = blockIdx.x * blockDim.x + threadIdx.x;
  const float s = sp[0];
  const float zp = (float)zpp[0];
  float4 v = ((const float4*)x)[i];
  float t0 = fminf(fmaxf(rintf(v.x / s) + zp, 0.f), 255.f);
  float t1 = fminf(fmaxf(rintf(v.y / s) + zp, 0.f), 255.f);
  float t2 = fminf(fmaxf(rintf(v.z / s) + zp, 0.f), 255.f);
  float t3 = fminf(fmaxf(rintf(v.w / s) + zp, 0.f), 255.f);
  int b0 = (int)t0 - 128, b1 = (int)t1 - 128, b2 = (int)t2 - 128, b3 = (int)t3 - 128;
  ((int*)q)[i] = (b0 & 255) | ((b1 & 255) << 8) | ((b2 & 255) << 16) | (b3 << 24);
}

// ---------------------------------------------------------------------------
// 256x256 i8 GEMM, faithful m201-style phase cadence: 4 phases per K-tile,
// each phase = {quadrant ds_reads + 1 global_load_lds -> s_barrier ->
// lgkmcnt(0)+sched_barrier(0) -> setprio(1) -> 8 MFMA -> setprio(0) ->
// s_barrier}; vmcnt(8) ONCE per tile at ph3 end (counted, never 0 in loop).
// Quadrants: G0=aL*bL(6 rds), G1=aL*bH(2), G2=aH*bH(4), G3=aH*bL(0).
// Geometry: 512 thr = 8 waves (2M x 4N), per-wave 128x64 out, BK=64 B,
// mfma_i32_16x16x64_i8. LDS 4-slot ring (A16K+B16K) = 128 KB.
// Ledger: 4 stages/tile (1/phase); end-of-t vmcnt(8) leaves stages of t-1,t
// -> slot t+1 confirmed; barrier collectivizes per-wave vmcnt. Prologue
// stages slots 0,1,2, vmcnt(8) confirms slot 0. Tail: kstg clamps to 63 ->
// re-stages into dead slots (never read); uniform 64-tile body.
// Swizzle (0 conflicts R1-R8): phys 16B slot = g ^ ((row>>1)&3) on both the
// global staging source and the ds_read addr.
// B content permutation (validated R8): LDS row (b+16j+r) holds weight row
// (b+4r+j) -> epilogue n = base+4c+j consecutive -> full-line packed stores.
// ---------------------------------------------------------------------------
#define STAGE16(SRC, DST)                                                     \
  __builtin_amdgcn_global_load_lds(                                           \
      (const __attribute__((address_space(1))) void*)(SRC),                   \
      (__attribute__((address_space(3))) void*)(DST), 16, 0, 0)

#define RD(p) (*(const i32x4*)(p))

#define BAR __builtin_amdgcn_s_barrier()
#define LGKM0 asm volatile("s_waitcnt lgkmcnt(0)" ::: "memory")
#define SCHED0 __builtin_amdgcn_sched_barrier(0)

#define MF8(I0, AV, J0, BV)                                                   \
  _Pragma("unroll") for (int i_ = 0; i_ < 4; ++i_)                            \
      _Pragma("unroll") for (int j_ = 0; j_ < 2; ++j_)                        \
          acc[(I0) + i_][(J0) + j_] = __builtin_amdgcn_mfma_i32_16x16x64_i8(  \
              AV[i_], BV[j_], acc[(I0) + i_][(J0) + j_], 0, 0, 0);

#define TILE8(SLOT, KSTG)                                                     \
  {                                                                           \
    const char* sA_ = &lds[SLOT][0][0];                                       \
    const char* sB_ = &lds[SLOT][1][0];                                       \
    char* nA_ = &lds[((SLOT) + 3) & 3][0][0];                                 \
    char* nB_ = &lds[((SLOT) + 3) & 3][1][0];                                 \
    i32x4 aL[4], aH[4], bL[2], bH[2];                                         \
    /* ---- ph0: G0 = aL x bL ---- */                                         \
    _Pragma("unroll") for (int i_ = 0; i_ < 4; ++i_)                          \
        aL[i_] = RD(sA_ + aoff[i_]);                                          \
    bL[0] = RD(sB_ + boff[0]);                                                \
    bL[1] = RD(sB_ + boff[1]);                                                \
    STAGE16(asrc0 + (size_t)(KSTG), nA_ + o0_);                               \
    BAR; LGKM0; SCHED0;                                                       \
    __builtin_amdgcn_s_setprio(1); MF8(0, aL, 0, bL)                          \
    __builtin_amdgcn_s_setprio(0);                                            \
    BAR;                                                                      \
    /* ---- ph1: G1 = aL x bH ---- */                                         \
    bH[0] = RD(sB_ + boff[2]);                                                \
    bH[1] = RD(sB_ + boff[3]);                                                \
    STAGE16(asrc1 + (size_t)(KSTG), nA_ + o1_);                               \
    BAR; LGKM0; SCHED0;                                                       \
    __builtin_amdgcn_s_setprio(1); MF8(0, aL, 2, bH)                          \
    __builtin_amdgcn_s_setprio(0);                                            \
    BAR;                                                                      \
    /* ---- ph2: G2 = aH x bH ---- */                                         \
    _Pragma("unroll") for (int i_ = 0; i_ < 4; ++i_)                          \
        aH[i_] = RD(sA_ + aoff[4 + i_]);                                      \
    STAGE16(bsrc0 + (size_t)(KSTG), nB_ + o0_);                               \
    BAR; LGKM0; SCHED0;                                                       \
    __builtin_amdgcn_s_setprio(1); MF8(4, aH, 2, bH)                          \
    __builtin_amdgcn_s_setprio(0);                                            \
    BAR;                                                                      \
    /* ---- ph3: G3 = aH x bL (no reads) ---- */                              \
    STAGE16(bsrc1 + (size_t)(KSTG), nB_ + o1_);                               \
    BAR; SCHED0;                                                              \
    __builtin_amdgcn_s_setprio(1); MF8(4, aH, 0, bL)                          \
    __builtin_amdgcn_s_setprio(0);                                            \
    asm volatile("s_waitcnt vmcnt(8)" ::: "memory");                          \
    BAR;                                                                      \
  }

template <int WRITE_Q>
__global__ __launch_bounds__(512, 2) void gemm_kernel(
    const char* __restrict__ qa, const char* __restrict__ wb,
    const int* __restrict__ corr, const float* __restrict__ swp,
    const float* __restrict__ bias, const float* __restrict__ sp,
    const int* __restrict__ zpp, char* __restrict__ outq, float* __restrict__ outf) {
  __shared__ __align__(16) char lds[4][2][16384];  // 128 KB: 4-slot ring
  const int tid = threadIdx.x;
  const int lane = tid & 63;
  const int w = tid >> 6;
  const int wr = w >> 2;   // 0..1 (M)
  const int wc = w & 3;    // 0..3 (N)
  const int bid = blockIdx.x;
  const int bm = bid & 31;  // M/256 = 32, fastest: neighbors share B panel
  const int bn = bid >> 5;  // N/256 = 16
  const char* abase = qa + (size_t)bm * 256 * K_DIM;
  const char* bbase = wb + (size_t)bn * 256 * K_DIM;

  // --- per-thread staging constants (inverse-swizzled global sources) ---
  const int o0_ = tid * 16;
  const int o1_ = 8192 + tid * 16;
  const int r0_ = o0_ >> 6, r1_ = o1_ >> 6;
  const int g0_ = ((o0_ >> 4) & 3) ^ ((r0_ >> 1) & 3);
  const int g1_ = ((o1_ >> 4) & 3) ^ ((r1_ >> 1) & 3);
  const char* asrc0 = abase + (size_t)r0_ * K_DIM + g0_ * 16;
  const char* asrc1 = abase + (size_t)r1_ * K_DIM + g1_ * 16;
  // B content permutation: LDS row rho holds weight row (rho&~63)+4*(rho&15)+((rho>>4)&3)
  const int p0_ = (r0_ & ~63) + 4 * (r0_ & 15) + ((r0_ >> 4) & 3);
  const int p1_ = (r1_ & ~63) + 4 * (r1_ & 15) + ((r1_ >> 4) & 3);
  const char* bsrc0 = bbase + (size_t)p0_ * K_DIM + g0_ * 16;
  const char* bsrc1 = bbase + (size_t)p1_ * K_DIM + g1_ * 16;

  // --- per-thread ds_read byte offsets (swizzled) ---
  const int rr = lane & 15;
  const int g = lane >> 4;
  int aoff[8], boff[4];
#pragma unroll
  for (int i = 0; i < 8; ++i) {
    const int row = wr * 128 + i * 16 + rr;
    aoff[i] = (row << 6) + ((g ^ ((row >> 1) & 3)) << 4);
  }
#pragma unroll
  for (int j = 0; j < 4; ++j) {
    const int row = wc * 64 + j * 16 + rr;
    boff[j] = (row << 6) + ((g ^ ((row >> 1) & 3)) << 4);
  }

  i32x4 acc[8][4] = {};

  // --- prologue: stage slots 0,1,2; vmcnt(8) confirms slot 0 ---
  STAGE16(asrc0, &lds[0][0][o0_]); STAGE16(asrc1, &lds[0][0][o1_]);
  STAGE16(bsrc0, &lds[0][1][o0_]); STAGE16(bsrc1, &lds[0][1][o1_]);
  STAGE16(asrc0 + 64, &lds[1][0][o0_]); STAGE16(asrc1 + 64, &lds[1][0][o1_]);
  STAGE16(bsrc0 + 64, &lds[1][1][o0_]); STAGE16(bsrc1 + 64, &lds[1][1][o1_]);
  STAGE16(asrc0 + 128, &lds[2][0][o0_]); STAGE16(asrc1 + 128, &lds[2][0][o1_]);
  STAGE16(bsrc0 + 128, &lds[2][1][o0_]); STAGE16(bsrc1 + 128, &lds[2][1][o1_]);
  asm volatile("s_waitcnt vmcnt(8)" ::: "memory");  // slot 0 confirmed
  __builtin_amdgcn_s_barrier();

  // --- main loop: 64 uniform tiles (kstg clamps; dead-slot re-stage tail) ---
  for (int tb = 0; tb < KTILES / 4; ++tb) {
#pragma unroll
    for (int u = 0; u < 4; ++u) {
      const int t = tb * 4 + u;
      const int ks_ = (t + 3 < KTILES ? t + 3 : KTILES - 1) * 64;
      TILE8(u, ks_);
    }
  }
  asm volatile("s_waitcnt vmcnt(0)" ::: "memory");  // drain before exit

  // --- epilogue (validated R8): frag j, lane c -> n = nb4 + j ---
  const float s = sp[0];
  const float zpf = (float)zpp[0];
  const int m0 = bm * 256 + wr * 128 + (lane >> 4) * 4;
  const int nb4 = bn * 256 + wc * 64 + ((lane & 15) << 2);
  const int4 cr4 = *(const int4*)(corr + nb4);
  const float4 sw4 = *(const float4*)(swp + nb4);
  const float4 bb4 = *(const float4*)(bias + nb4);
  const float fs0 = s * sw4.x, fs1 = s * sw4.y, fs2 = s * sw4.z, fs3 = s * sw4.w;
#pragma unroll
  for (int i = 0; i < 8; ++i) {
#pragma unroll
    for (int q = 0; q < 4; ++q) {
      const int m = m0 + i * 16 + q;
      const float v0 = fs0 * (float)(acc[i][0][q] + cr4.x) + bb4.x;
      const float v1 = fs1 * (float)(acc[i][1][q] + cr4.y) + bb4.y;
      const float v2 = fs2 * (float)(acc[i][2][q] + cr4.z) + bb4.z;
      const float v3 = fs3 * (float)(acc[i][3][q] + cr4.w) + bb4.w;
      if (WRITE_Q) {
        const int b0i = (int)fminf(fmaxf(rintf(v0 / s) + zpf, 0.f), 255.f) - 128;
        const int b1i = (int)fminf(fmaxf(rintf(v1 / s) + zpf, 0.f), 255.f) - 128;
        const int b2i = (int)fminf(fmaxf(rintf(v2 / s) + zpf, 0.f), 255.f) - 128;
        const int b3i = (int)fminf(fmaxf(rintf(v3 / s) + zpf, 0.f), 255.f) - 128;
        const uint32_t pk = (uint32_t)(b0i & 255) | ((uint32_t)(b1i & 255) << 8) |
                            ((uint32_t)(b2i & 255) << 16) | ((uint32_t)b3i << 24);
        *(uint32_t*)(outq + (size_t)m * N_DIM + nb4) = pk;
      } else {
        float4 o4;
        o4.x = v0; o4.y = v1; o4.z = v2; o4.w = v3;
        *(float4*)(outf + (size_t)m * N_DIM + nb4) = o4;
      }
    }
  }
}

// ---------------------------------------------------------------------------
extern "C" void kernel_launch(void* const* d_in, const int* in_sizes, int n_in,
                              void* d_out, int out_size, void* d_ws, size_t ws_size,
                              hipStream_t stream) {
  const float* x = (const float*)d_in[0];
  const int* wq = (const int*)d_in[1];
  const float* bias = (const float*)d_in[2];
  const float* s_in = (const float*)d_in[3];
  const int* zp_in = (const int*)d_in[4];
  const float* s_w = (const float*)d_in[5];
  float* out = (float*)d_out;

  const size_t WP_BYTES = (size_t)N_DIM * K_DIM;  // 16 MB packed int8 W
  const size_t Q_BYTES = (size_t)M_DIM * K_DIM;   // 32 MB int8 activations
  char* ws = (char*)d_ws;
  char* wp = ws;
  char* q1 = ws + WP_BYTES;
  char* q2 = q1 + Q_BYTES;
  int* corr = (int*)(q2 + Q_BYTES);
  const size_t NEEDED = WP_BYTES + 2 * Q_BYTES + (size_t)N_DIM * sizeof(int);
  if (ws_size < NEEDED) return;

  pack_w_kernel<<<N_DIM, 256, 0, stream>>>(wq, wp, corr, zp_in);
  quant_in_kernel<<<(M_DIM * K_DIM / 4) / 256, 256, 0, stream>>>(x, q1, s_in, zp_in);

  dim3 grid((M_DIM / 256) * (N_DIM / 256));  // 512 blocks
  dim3 blk(512);
  gemm_kernel<1><<<grid, blk, 0, stream>>>(q1, wp, corr, s_w, bias, s_in, zp_in, q2, nullptr);
  gemm_kernel<1><<<grid, blk, 0, stream>>>(q2, wp, corr, s_w, bias, s_in, zp_in, q1, nullptr);
  gemm_kernel<0><<<grid, blk, 0, stream>>>(q1, wp, corr, s_w, bias, s_in, zp_in, nullptr, out);
}